// Round 5
// baseline (352.065 us; speedup 1.0000x reference)
//
#include <hip/hip_runtime.h>

typedef __attribute__((ext_vector_type(8))) short s16x8;
typedef __attribute__((ext_vector_type(4))) float f32x4;

#define MFMA16 __builtin_amdgcn_mfma_f32_16x16x32_bf16
#define WAIT_VM0() asm volatile("s_waitcnt vmcnt(0)" ::: "memory")

__device__ __forceinline__ short f2bf(float x) {
  union { float f; unsigned u; } c; c.f = x;
  unsigned r = (c.u + 0x7fffu + ((c.u >> 16) & 1u)) >> 16;
  return (short)r;
}

__device__ __forceinline__ void gld16(const void* g, void* l) {
  __builtin_amdgcn_global_load_lds(
      (const __attribute__((address_space(1))) unsigned*)g,
      (__attribute__((address_space(3))) unsigned*)l, 16, 0, 0);
}

// BK=32 LDS tiles: rows 64 B = 4 slots; involution slot ^= (row>>1)&3 on BOTH
// the global source of global_load_lds and the ds_read (R3-verified, 0 conflicts):
//   stage (16-row strips): srow = lane>>2, selem = ((lane&3)^((lane>>3)&3))*8
//   read:                  koff = ((lane>>4)^((lane>>1)&3))*8
// P buffer [32 o][768 lw]: slot' = (lw>>3) ^ (o&7); b128 reads conflict-free
// per quarter-wave (slot'&7 bijective in lane&7).

// ---------------------------------------------------------------------------
// Prep
// ---------------------------------------------------------------------------
__global__ __launch_bounds__(256) void k_cvt_l1(const float* __restrict__ L1,
                                                short* __restrict__ L1b) {
  int i = blockIdx.x * 256 + threadIdx.x;
  L1b[i] = f2bf(L1[i]);
}

__global__ __launch_bounds__(256) void k_build_l2cat(const float* __restrict__ L2,
                                                     short* __restrict__ L2cat) {
  __shared__ float t[32][33];
  const int l = blockIdx.z, w0 = blockIdx.x * 32, z0 = blockIdx.y * 32;
  const int tx = threadIdx.x, ty = threadIdx.y;
  const float* src = L2 + (size_t)l * 65536;
  for (int i = ty; i < 32; i += 8) t[i][tx] = src[(size_t)(w0 + i) * 256 + z0 + tx];
  __syncthreads();
  for (int i = ty; i < 32; i += 8)
    L2cat[(size_t)(z0 + i) * 768 + l * 256 + w0 + tx] = f2bf(t[tx][i]);
}

__global__ __launch_bounds__(256) void k_build_wt(const float* __restrict__ W,
                                                  short* __restrict__ WT) {
  for (int idx = threadIdx.x + blockIdx.x * 256; idx < 192 * 192; idx += 256 * gridDim.x) {
    int lo = idx / 192, kf = idx % 192;
    int l = lo >> 6, o = lo & 63, k = kf / 64, f = kf & 63;
    WT[idx] = f2bf(W[(((size_t)(k * 3 + l) * 64 + f) << 6) + o]);
  }
}

__global__ __launch_bounds__(256) void k_cvt_ht(const float* __restrict__ H,
                                                short* __restrict__ HbT, int b0) {
  __shared__ float t[32][33];
  const int bc = blockIdx.z;
  const int wf0 = blockIdx.x * 32, v0 = blockIdx.y * 32;
  const int tx = threadIdx.x, ty = threadIdx.y;
  const float* src = H + ((size_t)(b0 + bc) * 256 + v0) * 16384;
  for (int i = ty; i < 32; i += 8) t[i][tx] = src[(size_t)i * 16384 + wf0 + tx];
  __syncthreads();
  short* dst = HbT + ((size_t)bc * 16384 + wf0) * 256;
  for (int i = ty; i < 32; i += 8) dst[(size_t)i * 256 + v0 + tx] = f2bf(t[tx][i]);
}

// ---------------------------------------------------------------------------
// S1: A2[((bc*256+u)*256+w)*192 + kk*64+f] = sum_v L1b[kk][u][v]*HbT[bc][w*64+f][v]
// 128x128 tile, BK=32, double-buffered + stage-before-compute.
// ---------------------------------------------------------------------------
__global__ __launch_bounds__(256, 4) void k_s1(const short* __restrict__ L1b,
                                               const short* __restrict__ HbT,
                                               short* __restrict__ A2) {
  __shared__ __align__(16) short At[2][128 * 32];
  __shared__ __align__(16) short Bt[2][128 * 32];
  const int t = threadIdx.x, lane = t & 63, wid = t >> 6;
  const int n0 = blockIdx.x * 128;
  const int kk = blockIdx.y >> 1;
  const int u0 = (blockIdx.y & 1) * 128;
  const int bc = blockIdx.z;
  const short* Ag = L1b + (size_t)kk * 65536;
  const short* Bg = HbT + (size_t)bc * 16384 * 256;
  const int wm = wid >> 1, wn = wid & 1;
  const int srow = lane >> 2;
  const int selem = ((lane & 3) ^ ((lane >> 3) & 3)) * 8;
  const int koff = ((lane >> 4) ^ ((lane >> 1) & 3)) * 8;
  const int ar = lane & 15;
#pragma unroll
  for (int j = 0; j < 2; ++j) {
    const int rb = wid * 32 + j * 16;
    gld16(Ag + (size_t)(u0 + rb + srow) * 256 + selem, At[0] + rb * 32);
    gld16(Bg + (size_t)(n0 + rb + srow) * 256 + selem, Bt[0] + rb * 32);
  }
  __syncthreads();
  f32x4 acc[4][4] = {};
#pragma unroll
  for (int kt8 = 0; kt8 < 8; ++kt8) {
    const int cur = kt8 & 1;
    s16x8 a[4], b[4];
#pragma unroll
    for (int i = 0; i < 4; ++i)
      a[i] = *(const s16x8*)&At[cur][(wm * 64 + i * 16 + ar) * 32 + koff];
#pragma unroll
    for (int j = 0; j < 4; ++j)
      b[j] = *(const s16x8*)&Bt[cur][(wn * 64 + j * 16 + ar) * 32 + koff];
    if (kt8 < 7) {
#pragma unroll
      for (int j = 0; j < 2; ++j) {
        const int rb = wid * 32 + j * 16;
        gld16(Ag + (size_t)(u0 + rb + srow) * 256 + (kt8 + 1) * 32 + selem, At[cur ^ 1] + rb * 32);
        gld16(Bg + (size_t)(n0 + rb + srow) * 256 + (kt8 + 1) * 32 + selem, Bt[cur ^ 1] + rb * 32);
      }
    }
#pragma unroll
    for (int i = 0; i < 4; ++i)
#pragma unroll
      for (int j = 0; j < 4; ++j) acc[i][j] = MFMA16(a[i], b[j], acc[i][j], 0, 0, 0);
    __syncthreads();
  }
  const int cr = lane >> 4, cc = lane & 15;
#pragma unroll
  for (int i = 0; i < 4; ++i)
#pragma unroll
    for (int j = 0; j < 4; ++j) {
      const int ncol = n0 + wn * 64 + j * 16 + cc;
      const int w = ncol >> 6, f = ncol & 63;
#pragma unroll
      for (int r = 0; r < 4; ++r) {
        const int u = u0 + wm * 64 + i * 16 + cr * 4 + r;
        A2[(((size_t)bc * 256 + u) * 256 + w) * 192 + kk * 64 + f] = f2bf(acc[i][j][r]);
      }
    }
}

// ---------------------------------------------------------------------------
// S2+S3 fused, split by o-half: 2 blocks per bu (o0 = 0 or 32).
// LDS union (80 KB -> 2 blocks/CU):
//   [0,48K):  Ws (phase1, 6x96x32) then P (32x768)
//   [48K,80K): At double buffer (2x256x32), phase1 = A2 tiles, phase2 = L2cat
// Both K-loops are barrier-free: each wave stages exactly the rows it reads.
// ---------------------------------------------------------------------------
__global__ __launch_bounds__(512, 4) void k_s23(const short* __restrict__ A2,
                                                const short* __restrict__ WTg,
                                                const short* __restrict__ L2cat,
                                                const float* __restrict__ bias,
                                                float* __restrict__ out, int b0) {
  __shared__ __align__(16) char lds[81920];
  short* P   = (short*)lds;
  short* Ws  = (short*)lds;
  short* AtS = (short*)(lds + 49152);
  const int t = threadIdx.x, lane = t & 63, wid = t >> 6;
  const int bx = blockIdx.x;
  const int bul = (bx & 7) | ((bx >> 4) << 3);   // pair (bul, o-half) 8 blocks apart -> same XCD
  const int o0 = ((bx >> 3) & 1) * 32;
  const int ar = lane & 15, cc = ar, cr = lane >> 4, sl = lane & 7;
  const int srow = lane >> 2;
  const int selem = ((lane & 3) ^ ((lane >> 3) & 3)) * 8;
  const int koff = ((lane >> 4) ^ ((lane >> 1) & 3)) * 8;
  const short* A2g = A2 + (size_t)bul * 49152;

  // prologue: full WT preload (rows l*64+o0+o32) + A2 kt=0
  for (int s = wid; s < 36; s += 8) {
    const int t6 = s / 6, rb = (s % 6) * 16;
    const int gr = (rb >> 5) * 64 + o0 + (rb & 31);
    gld16(WTg + (size_t)(gr + srow) * 192 + t6 * 32 + selem, Ws + (t6 * 96 + rb) * 32);
  }
#pragma unroll
  for (int is = 0; is < 2; ++is)
    gld16(A2g + (size_t)(wid * 32 + is * 16 + srow) * 192 + selem,
          AtS + (wid * 32 + is * 16) * 32);
  __syncthreads();

  // ---- Phase 1: acc[l][j][i] over (96 lo') x (own 32 w) x K=192 ----
  f32x4 acc[3][2][2] = {};
#pragma unroll
  for (int kt6 = 0; kt6 < 6; ++kt6) {
    const int cur = kt6 & 1;
    WAIT_VM0();
    s16x8 a[2];
#pragma unroll
    for (int i = 0; i < 2; ++i)
      a[i] = *(const s16x8*)&AtS[(cur * 256 + wid * 32 + i * 16 + ar) * 32 + koff];
    s16x8 b[3][2];
#pragma unroll
    for (int l = 0; l < 3; ++l)
#pragma unroll
      for (int j = 0; j < 2; ++j)
        b[l][j] = *(const s16x8*)&Ws[(kt6 * 96 + l * 32 + j * 16 + ar) * 32 + koff];
    if (kt6 < 5) {
#pragma unroll
      for (int is = 0; is < 2; ++is)
        gld16(A2g + (size_t)(wid * 32 + is * 16 + srow) * 192 + (kt6 + 1) * 32 + selem,
              AtS + ((cur ^ 1) * 256 + wid * 32 + is * 16) * 32);
    }
#pragma unroll
    for (int l = 0; l < 3; ++l)
#pragma unroll
      for (int j = 0; j < 2; ++j)
#pragma unroll
        for (int i = 0; i < 2; ++i)
          acc[l][j][i] = MFMA16(a[i], b[l][j], acc[l][j][i], 0, 0, 0);
  }

  __syncthreads();  // all phase-1 reads done; Ws region becomes P

  // acc -> P (packed b32, swizzled slots)
#pragma unroll
  for (int l = 0; l < 3; ++l)
#pragma unroll
    for (int j = 0; j < 2; ++j)
#pragma unroll
      for (int i = 0; i < 2; ++i)
#pragma unroll
        for (int rp = 0; rp < 2; ++rp) {
          const int r = rp * 2;
          const int w = wid * 32 + i * 16 + cr * 4 + r;
          const int o = j * 16 + cc;
          const int lw = l * 256 + w;
          const int addr = o * 768 + ((lw >> 3) ^ (o & 7)) * 8 + (lw & 7);
          unsigned lo16 = (unsigned short)f2bf(acc[l][j][i][r]);
          unsigned hi16 = (unsigned short)f2bf(acc[l][j][i][r + 1]);
          *(unsigned*)&P[addr] = lo16 | (hi16 << 16);
        }
  // phase-2 prologue stage (disjoint LDS region, overlaps P visibility barrier)
#pragma unroll
  for (int is = 0; is < 2; ++is)
    gld16(L2cat + (size_t)(wid * 32 + is * 16 + srow) * 768 + selem,
          AtS + (wid * 32 + is * 16) * 32);
  __syncthreads();  // drains ds_writes (P visible) + stage

  // ---- Phase 2: out tile (own 32 z) x (32 o) over K=768 ----
  f32x4 acc2[2][2] = {};
#pragma unroll
  for (int t2 = 0; t2 < 24; ++t2) {
    const int cur = t2 & 1;
    const int kt = t2 * 32;
    WAIT_VM0();
    s16x8 a[2], b[2];
#pragma unroll
    for (int i = 0; i < 2; ++i)
      a[i] = *(const s16x8*)&AtS[(cur * 256 + wid * 32 + i * 16 + ar) * 32 + koff];
#pragma unroll
    for (int j = 0; j < 2; ++j) {
      const int S = (kt >> 3) + (lane >> 4);
      b[j] = *(const s16x8*)&P[(j * 16 + ar) * 768 + (S ^ sl) * 8];
    }
    if (t2 < 23) {
#pragma unroll
      for (int is = 0; is < 2; ++is)
        gld16(L2cat + (size_t)(wid * 32 + is * 16 + srow) * 768 + (t2 + 1) * 32 + selem,
              AtS + ((cur ^ 1) * 256 + wid * 32 + is * 16) * 32);
    }
#pragma unroll
    for (int i = 0; i < 2; ++i)
#pragma unroll
      for (int j = 0; j < 2; ++j) acc2[i][j] = MFMA16(a[i], b[j], acc2[i][j], 0, 0, 0);
  }

  // epilogue
  float* og = out + ((size_t)b0 * 256 + bul) * 16384;
#pragma unroll
  for (int i = 0; i < 2; ++i)
#pragma unroll
    for (int j = 0; j < 2; ++j) {
      const float bv = bias[o0 + j * 16 + cc];
#pragma unroll
      for (int r = 0; r < 4; ++r) {
        const int z = wid * 32 + i * 16 + cr * 4 + r;
        og[(size_t)z * 64 + o0 + j * 16 + cc] = fmaxf(acc2[i][j][r] + bv, 0.f);
      }
    }
}

// ---------------------------------------------------------------------------
extern "C" void kernel_launch(void* const* d_in, const int* in_sizes, int n_in,
                              void* d_out, int out_size, void* d_ws, size_t ws_size,
                              hipStream_t stream) {
  const float* H    = (const float*)d_in[0];
  const float* L1   = (const float*)d_in[1];
  const float* L2   = (const float*)d_in[2];
  const float* W    = (const float*)d_in[3];
  const float* bias = (const float*)d_in[4];
  float* out = (float*)d_out;

  char* ws = (char*)d_ws;
  short* L1b   = (short*)ws;                  // 384 KB
  short* L2cat = (short*)(ws + (384 << 10));  // 384 KB
  short* WT    = (short*)(ws + (768 << 10));  // 72 KB
  char* data = ws + (4ull << 20);

  // per-batch: HbT 8 MiB + A2 24 MiB = 32 MiB
  const size_t perb = 32ull << 20;
  size_t avail = (ws_size > (4ull << 20)) ? ws_size - (4ull << 20) : 0;
  int nb = 1;
  if (avail >= 8 * perb) nb = 8;
  else if (avail >= 4 * perb) nb = 4;
  else if (avail >= 2 * perb) nb = 2;

  short* HbT = (short*)data;
  short* A2  = (short*)(data + (size_t)nb * (8ull << 20));

  k_cvt_l1<<<768, 256, 0, stream>>>(L1, L1b);
  k_build_l2cat<<<dim3(8, 8, 3), dim3(32, 8), 0, stream>>>(L2, L2cat);
  k_build_wt<<<36, 256, 0, stream>>>(W, WT);

  for (int b0 = 0; b0 < 8; b0 += nb) {
    k_cvt_ht<<<dim3(512, 8, nb), dim3(32, 8), 0, stream>>>(H, HbT, b0);
    k_s1<<<dim3(128, 6, nb), 256, 0, stream>>>(L1b, HbT, A2);
    k_s23<<<nb * 512, 512, 0, stream>>>(A2, WT, L2cat, bias, out, b0);
  }
}